// Round 8
// baseline (186.213 us; speedup 1.0000x reference)
//
#include <hip/hip_runtime.h>
#include <stdint.h>

typedef __attribute__((ext_vector_type(8))) short short8;
typedef __attribute__((ext_vector_type(4))) short bf16x4;
typedef __attribute__((ext_vector_type(4))) float f32x4;

#define MFMA32(a, b, c) __builtin_amdgcn_mfma_f32_16x16x32_bf16((a), (b), (c), 0, 0, 0)
#define MFMA16(a, b, c) __builtin_amdgcn_mfma_f32_16x16x16bf16_1k((a), (b), (c), 0, 0, 0)

__device__ __forceinline__ uint16_t f32_to_bf16(float f) {
  union { float f; uint32_t u; } v; v.f = f;
  uint32_t u = v.u;
  u += 0x7FFFu + ((u >> 16) & 1u);   // RTNE
  return (uint16_t)(u >> 16);
}
__device__ __forceinline__ uint16_t f32_to_bf16_fast(float f) {
  union { float f; uint32_t u; } v; v.f = f;
  return (uint16_t)((v.u + 0x8000u) >> 16);   // round-half-up (P only)
}

__device__ __forceinline__ void load_lds16(const uint16_t* g, uint16_t* l) {
  __builtin_amdgcn_global_load_lds(
      (const __attribute__((address_space(1))) uint32_t*)g,
      (__attribute__((address_space(3))) uint32_t*)l, 16, 0, 0);
}

// ---------------- fused f32 -> bf16 conversion (x, Wqkv, Wout) ----------------
__global__ __launch_bounds__(256) void cvt3_kernel(
    const float* __restrict__ x, const float* __restrict__ w1,
    const float* __restrict__ w2, uint16_t* __restrict__ xb,
    uint16_t* __restrict__ w1b, uint16_t* __restrict__ w2b) {
  const int i = blockIdx.x * 256 + threadIdx.x;  // 2,097,152 float4 total
  const float4* src;
  ushort4* dst;
  int off;
  if (i < 1048576) { src = (const float4*)x;  dst = (ushort4*)xb;  off = i; }
  else if (i < 1835008) { src = (const float4*)w1; dst = (ushort4*)w1b; off = i - 1048576; }
  else { src = (const float4*)w2; dst = (ushort4*)w2b; off = i - 1835008; }
  const float4 v = src[off];
  ushort4 o;
  o.x = f32_to_bf16(v.x);
  o.y = f32_to_bf16(v.y);
  o.z = f32_to_bf16(v.z);
  o.w = f32_to_bf16(v.w);
  dst[off] = o;
}

// ---------------- QKV GEMM: 128x128 tile, BK=64, single-buffer serial (R7, proven) ----------------
__global__ __launch_bounds__(256) void gemm_qkv_kernel(
    const uint16_t* __restrict__ A, const uint16_t* __restrict__ Bt,
    uint16_t* __restrict__ Qh, uint16_t* __restrict__ Kh, uint16_t* __restrict__ Vh) {
  __shared__ __align__(16) uint16_t As[128 * 64];   // 16 KB
  __shared__ __align__(16) uint16_t Bs[128 * 64];   // 16 KB
  const int tid = threadIdx.x;
  const int wave = tid >> 6;
  const int lane = tid & 63;
  const int quad = lane >> 4;
  const int l16 = lane & 15;
  const int row0 = blockIdx.x * 128;
  const int col0 = blockIdx.y * 128;
  const int wm = (wave >> 1) * 64;
  const int wn = (wave & 1) * 64;
  const int K = 1024;

  f32x4 acc[4][4];
#pragma unroll
  for (int a = 0; a < 4; ++a)
#pragma unroll
    for (int b = 0; b < 4; ++b) acc[a][b] = (f32x4){0.f, 0.f, 0.f, 0.f};

  // staging: source chunk pre-swizzled (T2 write side); read swizzle cancels it.
  const int swz8 = ((lane & 7) ^ ((lane >> 3) & 7)) * 8;
  const uint16_t* gA = A + (size_t)(row0 + wave * 32 + (lane >> 3)) * K + swz8;
  const uint16_t* gB = Bt + (size_t)(col0 + wave * 32 + (lane >> 3)) * K + swz8;

  for (int k0 = 0; k0 < K; k0 += 64) {
#pragma unroll
    for (int s = 0; s < 4; ++s) {
      load_lds16(gA + (size_t)s * 8 * K + k0, &As[(wave * 32 + s * 8) * 64]);
      load_lds16(gB + (size_t)s * 8 * K + k0, &Bs[(wave * 32 + s * 8) * 64]);
    }
    __syncthreads();
#pragma unroll
    for (int ks = 0; ks < 2; ++ks) {
      const int cswz = (((ks * 4 + quad) ^ (l16 & 7)) * 8);
      short8 af[4], bf[4];
#pragma unroll
      for (int mt = 0; mt < 4; ++mt)
        af[mt] = *(const short8*)&As[(wm + mt * 16 + l16) * 64 + cswz];
#pragma unroll
      for (int nt = 0; nt < 4; ++nt)
        bf[nt] = *(const short8*)&Bs[(wn + nt * 16 + l16) * 64 + cswz];
#pragma unroll
      for (int mt = 0; mt < 4; ++mt)
#pragma unroll
        for (int nt = 0; nt < 4; ++nt)
          acc[mt][nt] = MFMA32(af[mt], bf[nt], acc[mt][nt]);
    }
    __syncthreads();
  }

  // epilogue: qkv swizzle (verbatim from the proven R3 MODE-1 epilogue)
#pragma unroll
  for (int mt = 0; mt < 4; ++mt) {
#pragma unroll
    for (int nt = 0; nt < 4; ++nt) {
      const int col = col0 + wn + nt * 16 + l16;
      const int which = col >> 10;          // 0=q 1=k 2=v (block-uniform)
      const int hc = (col & 1023) >> 6;
      const int d = col & 63;
#pragma unroll
      for (int r = 0; r < 4; ++r) {
        const int row = row0 + wm + mt * 16 + quad * 4 + r;
        const float val = acc[mt][nt][r];
        const int b = row >> 11;
        const int nn = row & 2047;
        const size_t hb = (size_t)(b * 16 + hc) * 131072;
        if (which == 0) {
          // fold softmax scale (1/8) and log2(e) into Q
          Qh[hb + (size_t)nn * 64 + d] = f32_to_bf16(val * 0.1803368801111244f);
        } else if (which == 1) {
          const uint16_t bv = f32_to_bf16(val);
          // K: 16x16x32 A-frag order [jt][st][kc][lane=qd*16+j16][e8]
          const int jt = nn >> 6, st = (nn >> 4) & 3, j16 = nn & 15;
          const int kc = d >> 5, qd = (d >> 3) & 3, e = d & 7;
          Kh[hb + jt * 4096 + st * 1024 + kc * 512 + (qd * 16 + j16) * 8 + e] = bv;
        } else {
          const uint16_t bv = f32_to_bf16(val);
          // V: 16x16x16 B-frag order [jt][st][tth][lane=qv*16+d16][ttl][e4]
          const int jt = nn >> 6, j = nn & 63;
          const int st = j >> 4, qv = (j >> 2) & 3, e = j & 3;
          const int tt = d >> 4, d16 = d & 15;
          Vh[hb + jt * 4096 + ((st * 2 + (tt >> 1)) * 64 + qv * 16 + d16) * 8 +
             (tt & 1) * 4 + e] = bv;
        }
      }
    }
  }
}

// ---------------- output-proj GEMM: 128x64 tile, BK=64, single-buffer serial (R7, proven) ----------------
__global__ __launch_bounds__(256) void gemm_out_kernel(
    const uint16_t* __restrict__ A, const uint16_t* __restrict__ Bt,
    float* __restrict__ Cf, const float* __restrict__ bias) {
  __shared__ __align__(16) uint16_t As[128 * 64];   // 16 KB
  __shared__ __align__(16) uint16_t Bs[64 * 64];    // 8 KB
  const int tid = threadIdx.x;
  const int wave = tid >> 6;
  const int lane = tid & 63;
  const int quad = lane >> 4;
  const int l16 = lane & 15;
  const int row0 = blockIdx.x * 128;
  const int col0 = blockIdx.y * 64;
  const int wm = (wave >> 1) * 64;
  const int wn = (wave & 1) * 32;
  const int K = 1024;
  const int N = 1024;

  f32x4 acc[4][2];
#pragma unroll
  for (int a = 0; a < 4; ++a)
#pragma unroll
    for (int b = 0; b < 2; ++b) acc[a][b] = (f32x4){0.f, 0.f, 0.f, 0.f};

  const int swz8 = ((lane & 7) ^ ((lane >> 3) & 7)) * 8;
  const uint16_t* gA = A + (size_t)(row0 + wave * 32 + (lane >> 3)) * K + swz8;
  const uint16_t* gB = Bt + (size_t)(col0 + wave * 16 + (lane >> 3)) * K + swz8;

  for (int k0 = 0; k0 < K; k0 += 64) {
#pragma unroll
    for (int s = 0; s < 4; ++s)
      load_lds16(gA + (size_t)s * 8 * K + k0, &As[(wave * 32 + s * 8) * 64]);
#pragma unroll
    for (int s = 0; s < 2; ++s)
      load_lds16(gB + (size_t)s * 8 * K + k0, &Bs[(wave * 16 + s * 8) * 64]);
    __syncthreads();
#pragma unroll
    for (int ks = 0; ks < 2; ++ks) {
      const int cswz = (((ks * 4 + quad) ^ (l16 & 7)) * 8);
      short8 af[4], bf[2];
#pragma unroll
      for (int mt = 0; mt < 4; ++mt)
        af[mt] = *(const short8*)&As[(wm + mt * 16 + l16) * 64 + cswz];
#pragma unroll
      for (int nt = 0; nt < 2; ++nt)
        bf[nt] = *(const short8*)&Bs[(wn + nt * 16 + l16) * 64 + cswz];
#pragma unroll
      for (int mt = 0; mt < 4; ++mt)
#pragma unroll
        for (int nt = 0; nt < 2; ++nt)
          acc[mt][nt] = MFMA32(af[mt], bf[nt], acc[mt][nt]);
    }
    __syncthreads();
  }

#pragma unroll
  for (int mt = 0; mt < 4; ++mt) {
#pragma unroll
    for (int nt = 0; nt < 2; ++nt) {
      const int col = col0 + wn + nt * 16 + l16;
#pragma unroll
      for (int r = 0; r < 4; ++r) {
        const int row = row0 + wm + mt * 16 + quad * 4 + r;
        Cf[(size_t)row * N + col] = acc[mt][nt][r] + bias[col];
      }
    }
  }
}

// ---------------- flash attention, LDS-shared KV, 64-row blocks ----------------
// R7 counters: 54 us at Occupancy 17.7% (grid 512 = 2 blocks/CU), MfmaUtil 43,
// VALUBusy 36 -> MFMA pipe idle 57%, within-wave MFMA->exp2->pack chain has
// only 1 other wave/SIMD to overlap with. Fix: split each 128-row block into
// two 64-row blocks (4 waves x 16 q-rows) -> 1024 blocks = 4 blocks/CU =
// 4 waves/SIMD. Unlike R1 (pre-LDS, traffic scaled with waves -> 2 GB, wall),
// traffic now scales with BLOCKS: 512 MB from L2/L3, well under the 34.5 TB/s
// wall. Compute totals identical; pure latency hiding.
// Head->XCD swizzle: block bx = g*8 + (h&7); assuming round-robin bx%8->XCD,
// all blocks of head h land on XCD h&7 -> per-XCD L2 K/V working set = 4 heads
// x 512 KB = 2 MB < 4 MB (vs 16 MB unswizzled). Speed heuristic only.
__global__ __launch_bounds__(256, 4) void attn_kernel(
    const uint16_t* __restrict__ Qh, const uint16_t* __restrict__ Kh,
    const uint16_t* __restrict__ Vh, uint16_t* __restrict__ out) {
  __shared__ __align__(16) uint16_t Ks[2][4096];
  __shared__ __align__(16) uint16_t Vs[2][4096];
  const int tid = threadIdx.x;
  const int wave = tid >> 6;
  const int lane = tid & 63;
  const int quad = lane >> 4;
  const int l16 = lane & 15;
  const int bx = blockIdx.x;
  // bx = g*8 + xcd ; g = it + 32*hhi + 64*ib ; h = hhi*8 + xcd
  const int xcd = bx & 7;
  const int g = bx >> 3;
  const int it = g & 31;            // 32 i-tiles of 64 rows
  const int h = ((g >> 5) & 1) * 8 + xcd;
  const int ib = g >> 6;
  const int i0 = it * 64 + wave * 16;
  const size_t hb = (size_t)(ib * 16 + h) * 131072;

  // Q fragments (B-operand of S^T MFMA): lane l16 = q-row, k = quad*8+e
  short8 qf[2];
#pragma unroll
  for (int kc = 0; kc < 2; ++kc)
    qf[kc] = *(const short8*)(Qh + hb + (size_t)(i0 + l16) * 64 + kc * 32 + quad * 8);

  f32x4 o[4], o4;
  o4 = (f32x4){0.f, 0.f, 0.f, 0.f};
#pragma unroll
  for (int t = 0; t < 4; ++t) o[t] = (f32x4){0.f, 0.f, 0.f, 0.f};

  const bf16x4 ones4 = {(short)0x3F80, (short)0x3F80, (short)0x3F80, (short)0x3F80};

  // staging: this wave stages elems [wave*1024, wave*1024+1024) of each tile
  const uint16_t* gK = Kh + hb + wave * 1024 + lane * 8;
  const uint16_t* gV = Vh + hb + wave * 1024 + lane * 8;
  const int so = wave * 1024;

  // prologue: stage tile 0 into buf 0
  load_lds16(gK, &Ks[0][so]);
  load_lds16(gK + 512, &Ks[0][so + 512]);
  load_lds16(gV, &Vs[0][so]);
  load_lds16(gV + 512, &Vs[0][so + 512]);
  __syncthreads();

#pragma unroll 2
  for (int t = 0; t < 32; ++t) {
    const int cur = t & 1;
    // stage tile t+1 into the other buffer (hidden under this tile's compute)
    if (t < 31) {
      const size_t goff = (size_t)(t + 1) * 4096;
      load_lds16(gK + goff, &Ks[cur ^ 1][so]);
      load_lds16(gK + goff + 512, &Ks[cur ^ 1][so + 512]);
      load_lds16(gV + goff, &Vs[cur ^ 1][so]);
      load_lds16(gV + goff + 512, &Vs[cur ^ 1][so + 512]);
    }

    // K frags from LDS (same frag order as the global layout)
    short8 kf[8];
#pragma unroll
    for (int i = 0; i < 8; ++i) kf[i] = *(const short8*)&Ks[cur][i * 512 + lane * 8];

    // S^T = K . Q^T : lane holds q-row l16, j = st*16 + quad*4 + r
    f32x4 s[4];
#pragma unroll
    for (int st = 0; st < 4; ++st) {
      f32x4 sc = (f32x4){0.f, 0.f, 0.f, 0.f};
      sc = MFMA32(kf[st * 2 + 0], qf[0], sc);
      sc = MFMA32(kf[st * 2 + 1], qf[1], sc);
      s[st] = sc;
    }

    // V frags (issue ds_reads while exp2 runs)
    short8 v8[8];
#pragma unroll
    for (int i = 0; i < 8; ++i) v8[i] = *(const short8*)&Vs[cur][i * 512 + lane * 8];

    // P = exp2(s), packed straight into 16x16x16 A-frags (k = quad*4 + e)
    bf16x4 p4[4];
#pragma unroll
    for (int st = 0; st < 4; ++st) {
      bf16x4 p;
#pragma unroll
      for (int r = 0; r < 4; ++r)
        p[r] = (short)f32_to_bf16_fast(__builtin_amdgcn_exp2f(s[st][r]));
      p4[st] = p;
    }

    // O += P V (16x16x16), row sums via ones-column
#pragma unroll
    for (int st = 0; st < 4; ++st) {
      o4 = MFMA16(p4[st], ones4, o4);
#pragma unroll
      for (int tth = 0; tth < 2; ++tth) {
        const short8 w = v8[st * 2 + tth];
        const bf16x4 vlo = {w[0], w[1], w[2], w[3]};
        const bf16x4 vhi = {w[4], w[5], w[6], w[7]};
        o[tth * 2 + 0] = MFMA16(p4[st], vlo, o[tth * 2 + 0]);
        o[tth * 2 + 1] = MFMA16(p4[st], vhi, o[tth * 2 + 1]);
      }
    }

    __syncthreads();
  }

  // epilogue: O /= l, store bf16 [B*2048][1024]
#pragma unroll
  for (int r = 0; r < 4; ++r) {
    const float inv = 1.0f / o4[r];
    const int row = i0 + quad * 4 + r;
    const size_t obase = (size_t)(ib * 2048 + row) * 1024 + h * 64;
#pragma unroll
    for (int tt = 0; tt < 4; ++tt)
      out[obase + tt * 16 + l16] = f32_to_bf16(o[tt][r] * inv);
  }
}

// ---------------- launch ----------------
extern "C" void kernel_launch(void* const* d_in, const int* in_sizes, int n_in,
                              void* d_out, int out_size, void* d_ws, size_t ws_size,
                              hipStream_t stream) {
  const float* x = (const float*)d_in[0];     // [2,2048,1024]
  const float* Wqkv = (const float*)d_in[1];  // [3072,1024]
  const float* Wout = (const float*)d_in[2];  // [1024,1024]
  const float* bout = (const float*)d_in[3];  // [1024]

  uint16_t* xb = (uint16_t*)d_ws;                       // 4096*1024
  uint16_t* wqkvb = xb + (size_t)4096 * 1024;           // 3072*1024
  uint16_t* woutb = wqkvb + (size_t)3072 * 1024;        // 1024*1024
  uint16_t* qh = woutb + (size_t)1024 * 1024;           // 32 heads * 131072
  uint16_t* kh = qh + (size_t)32 * 131072;
  uint16_t* vh = kh + (size_t)32 * 131072;
  uint16_t* attnb = vh + (size_t)32 * 131072;           // 4096*1024

  cvt3_kernel<<<8192, 256, 0, stream>>>(x, Wqkv, Wout, xb, wqkvb, woutb);

  gemm_qkv_kernel<<<dim3(4096 / 128, 3072 / 128), 256, 0, stream>>>(
      xb, wqkvb, qh, kh, vh);

  attn_kernel<<<1024, 256, 0, stream>>>(qh, kh, vh, attnb);

  gemm_out_kernel<<<dim3(4096 / 128, 1024 / 64), 256, 0, stream>>>(
      attnb, woutb, (float*)d_out, bout);
}

// Round 9
// 182.903 us; speedup vs baseline: 1.0181x; 1.0181x over previous
//
#include <hip/hip_runtime.h>
#include <stdint.h>

typedef __attribute__((ext_vector_type(8))) short short8;
typedef __attribute__((ext_vector_type(4))) short bf16x4;
typedef __attribute__((ext_vector_type(4))) float f32x4;

#define MFMA32(a, b, c) __builtin_amdgcn_mfma_f32_16x16x32_bf16((a), (b), (c), 0, 0, 0)

__device__ __forceinline__ uint16_t f32_to_bf16(float f) {
  union { float f; uint32_t u; } v; v.f = f;
  uint32_t u = v.u;
  u += 0x7FFFu + ((u >> 16) & 1u);   // RTNE
  return (uint16_t)(u >> 16);
}
__device__ __forceinline__ uint16_t f32_to_bf16_fast(float f) {
  union { float f; uint32_t u; } v; v.f = f;
  return (uint16_t)((v.u + 0x8000u) >> 16);   // round-half-up (P only)
}

__device__ __forceinline__ void load_lds16(const uint16_t* g, uint16_t* l) {
  __builtin_amdgcn_global_load_lds(
      (const __attribute__((address_space(1))) uint32_t*)g,
      (__attribute__((address_space(3))) uint32_t*)l, 16, 0, 0);
}

// ---------------- fused f32 -> bf16 conversion (x, Wqkv, Wout) ----------------
__global__ __launch_bounds__(256) void cvt3_kernel(
    const float* __restrict__ x, const float* __restrict__ w1,
    const float* __restrict__ w2, uint16_t* __restrict__ xb,
    uint16_t* __restrict__ w1b, uint16_t* __restrict__ w2b) {
  const int i = blockIdx.x * 256 + threadIdx.x;  // 2,097,152 float4 total
  const float4* src;
  ushort4* dst;
  int off;
  if (i < 1048576) { src = (const float4*)x;  dst = (ushort4*)xb;  off = i; }
  else if (i < 1835008) { src = (const float4*)w1; dst = (ushort4*)w1b; off = i - 1048576; }
  else { src = (const float4*)w2; dst = (ushort4*)w2b; off = i - 1835008; }
  const float4 v = src[off];
  ushort4 o;
  o.x = f32_to_bf16(v.x);
  o.y = f32_to_bf16(v.y);
  o.z = f32_to_bf16(v.z);
  o.w = f32_to_bf16(v.w);
  dst[off] = o;
}

// ---------------- QKV GEMM: 128x128 tile, BK=64, single-buffer serial (R7, proven) ----------------
// R9 change: V epilogue layout only. V is now stored as the B-operand frag of a
// PV MFMA 16x16x32 with j-axis permutation sigma(8q+e) = (e>>2)*16 + q*4 + (e&3)
// -- chosen so the P values a lane naturally holds after S^T (j = st*16+quad*4+r)
// form a valid x32 A-frag with ZERO cross-lane shuffles. k is a summation index,
// so A and B may share any permutation as long as it's the SAME one.
__global__ __launch_bounds__(256) void gemm_qkv_kernel(
    const uint16_t* __restrict__ A, const uint16_t* __restrict__ Bt,
    uint16_t* __restrict__ Qh, uint16_t* __restrict__ Kh, uint16_t* __restrict__ Vh) {
  __shared__ __align__(16) uint16_t As[128 * 64];   // 16 KB
  __shared__ __align__(16) uint16_t Bs[128 * 64];   // 16 KB
  const int tid = threadIdx.x;
  const int wave = tid >> 6;
  const int lane = tid & 63;
  const int quad = lane >> 4;
  const int l16 = lane & 15;
  const int row0 = blockIdx.x * 128;
  const int col0 = blockIdx.y * 128;
  const int wm = (wave >> 1) * 64;
  const int wn = (wave & 1) * 64;
  const int K = 1024;

  f32x4 acc[4][4];
#pragma unroll
  for (int a = 0; a < 4; ++a)
#pragma unroll
    for (int b = 0; b < 4; ++b) acc[a][b] = (f32x4){0.f, 0.f, 0.f, 0.f};

  // staging: source chunk pre-swizzled (T2 write side); read swizzle cancels it.
  const int swz8 = ((lane & 7) ^ ((lane >> 3) & 7)) * 8;
  const uint16_t* gA = A + (size_t)(row0 + wave * 32 + (lane >> 3)) * K + swz8;
  const uint16_t* gB = Bt + (size_t)(col0 + wave * 32 + (lane >> 3)) * K + swz8;

  for (int k0 = 0; k0 < K; k0 += 64) {
#pragma unroll
    for (int s = 0; s < 4; ++s) {
      load_lds16(gA + (size_t)s * 8 * K + k0, &As[(wave * 32 + s * 8) * 64]);
      load_lds16(gB + (size_t)s * 8 * K + k0, &Bs[(wave * 32 + s * 8) * 64]);
    }
    __syncthreads();
#pragma unroll
    for (int ks = 0; ks < 2; ++ks) {
      const int cswz = (((ks * 4 + quad) ^ (l16 & 7)) * 8);
      short8 af[4], bf[4];
#pragma unroll
      for (int mt = 0; mt < 4; ++mt)
        af[mt] = *(const short8*)&As[(wm + mt * 16 + l16) * 64 + cswz];
#pragma unroll
      for (int nt = 0; nt < 4; ++nt)
        bf[nt] = *(const short8*)&Bs[(wn + nt * 16 + l16) * 64 + cswz];
#pragma unroll
      for (int mt = 0; mt < 4; ++mt)
#pragma unroll
        for (int nt = 0; nt < 4; ++nt)
          acc[mt][nt] = MFMA32(af[mt], bf[nt], acc[mt][nt]);
    }
    __syncthreads();
  }

  // epilogue: qkv swizzle
#pragma unroll
  for (int mt = 0; mt < 4; ++mt) {
#pragma unroll
    for (int nt = 0; nt < 4; ++nt) {
      const int col = col0 + wn + nt * 16 + l16;
      const int which = col >> 10;          // 0=q 1=k 2=v (block-uniform)
      const int hc = (col & 1023) >> 6;
      const int d = col & 63;
#pragma unroll
      for (int r = 0; r < 4; ++r) {
        const int row = row0 + wm + mt * 16 + quad * 4 + r;
        const float val = acc[mt][nt][r];
        const int b = row >> 11;
        const int nn = row & 2047;
        const size_t hb = (size_t)(b * 16 + hc) * 131072;
        if (which == 0) {
          // fold softmax scale (1/8) and log2(e) into Q
          Qh[hb + (size_t)nn * 64 + d] = f32_to_bf16(val * 0.1803368801111244f);
        } else if (which == 1) {
          const uint16_t bv = f32_to_bf16(val);
          // K: 16x16x32 A-frag order [jt][st][kc][lane=qd*16+j16][e8]
          const int jt = nn >> 6, st = (nn >> 4) & 3, j16 = nn & 15;
          const int kc = d >> 5, qd = (d >> 3) & 3, e = d & 7;
          Kh[hb + jt * 4096 + st * 1024 + kc * 512 + (qd * 16 + j16) * 8 + e] = bv;
        } else {
          const uint16_t bv = f32_to_bf16(val);
          // V: 16x16x32 B-frag, sigma-permuted j:
          //   j' = nn&63; st2 = j'>>5; j32 = j'&31;
          //   q = (j32>>2)&3; e = (j32>>4)*4 + (j32&3);
          //   off = jt*4096 + (st2*4 + dt)*512 + (q*16 + d16)*8 + e
          const int jt = nn >> 6, jp = nn & 63;
          const int st2 = jp >> 5, j32 = jp & 31;
          const int qv = (j32 >> 2) & 3, e = (j32 >> 4) * 4 + (j32 & 3);
          const int dt = d >> 4, d16 = d & 15;
          Vh[hb + jt * 4096 + (st2 * 4 + dt) * 512 + (qv * 16 + d16) * 8 + e] = bv;
        }
      }
    }
  }
}

// ---------------- output-proj GEMM: 128x64 tile, BK=64, single-buffer serial (R7, proven) ----------------
__global__ __launch_bounds__(256) void gemm_out_kernel(
    const uint16_t* __restrict__ A, const uint16_t* __restrict__ Bt,
    float* __restrict__ Cf, const float* __restrict__ bias) {
  __shared__ __align__(16) uint16_t As[128 * 64];   // 16 KB
  __shared__ __align__(16) uint16_t Bs[64 * 64];    // 8 KB
  const int tid = threadIdx.x;
  const int wave = tid >> 6;
  const int lane = tid & 63;
  const int quad = lane >> 4;
  const int l16 = lane & 15;
  const int row0 = blockIdx.x * 128;
  const int col0 = blockIdx.y * 64;
  const int wm = (wave >> 1) * 64;
  const int wn = (wave & 1) * 32;
  const int K = 1024;
  const int N = 1024;

  f32x4 acc[4][2];
#pragma unroll
  for (int a = 0; a < 4; ++a)
#pragma unroll
    for (int b = 0; b < 2; ++b) acc[a][b] = (f32x4){0.f, 0.f, 0.f, 0.f};

  const int swz8 = ((lane & 7) ^ ((lane >> 3) & 7)) * 8;
  const uint16_t* gA = A + (size_t)(row0 + wave * 32 + (lane >> 3)) * K + swz8;
  const uint16_t* gB = Bt + (size_t)(col0 + wave * 16 + (lane >> 3)) * K + swz8;

  for (int k0 = 0; k0 < K; k0 += 64) {
#pragma unroll
    for (int s = 0; s < 4; ++s)
      load_lds16(gA + (size_t)s * 8 * K + k0, &As[(wave * 32 + s * 8) * 64]);
#pragma unroll
    for (int s = 0; s < 2; ++s)
      load_lds16(gB + (size_t)s * 8 * K + k0, &Bs[(wave * 16 + s * 8) * 64]);
    __syncthreads();
#pragma unroll
    for (int ks = 0; ks < 2; ++ks) {
      const int cswz = (((ks * 4 + quad) ^ (l16 & 7)) * 8);
      short8 af[4], bf[2];
#pragma unroll
      for (int mt = 0; mt < 4; ++mt)
        af[mt] = *(const short8*)&As[(wm + mt * 16 + l16) * 64 + cswz];
#pragma unroll
      for (int nt = 0; nt < 2; ++nt)
        bf[nt] = *(const short8*)&Bs[(wn + nt * 16 + l16) * 64 + cswz];
#pragma unroll
      for (int mt = 0; mt < 4; ++mt)
#pragma unroll
        for (int nt = 0; nt < 2; ++nt)
          acc[mt][nt] = MFMA32(af[mt], bf[nt], acc[mt][nt]);
    }
    __syncthreads();
  }

#pragma unroll
  for (int mt = 0; mt < 4; ++mt) {
#pragma unroll
    for (int nt = 0; nt < 2; ++nt) {
      const int col = col0 + wn + nt * 16 + l16;
#pragma unroll
      for (int r = 0; r < 4; ++r) {
        const int row = row0 + wm + mt * 16 + quad * 4 + r;
        Cf[(size_t)row * N + col] = acc[mt][nt][r] + bias[col];
      }
    }
  }
}

// ---------------- flash attention, LDS-shared KV, 64-row blocks, MFMA32 PV ----------------
// R8 counters: MfmaUtil 43 + VALUBusy 38 = 81% -> pipes jointly near co-issue
// limit; occupancy lever exhausted. R9: PV switched from 20x mfma_16x16x16 to
// 8x mfma_16x16x32 + 2 row-sum (j-axis sigma-permutation shared by P and V;
// V stored pre-permuted by the GEMM epilogue -> zero shuffles, same LDS
// addresses, same output C layout). ~18 uniform MFMA32/tile vs 8+20 mixed.
// Head->XCD swizzle kept (FETCH 69.7 -> 12.3 MB measured, K/V L2-resident).
__global__ __launch_bounds__(256, 4) void attn_kernel(
    const uint16_t* __restrict__ Qh, const uint16_t* __restrict__ Kh,
    const uint16_t* __restrict__ Vh, uint16_t* __restrict__ out) {
  __shared__ __align__(16) uint16_t Ks[2][4096];
  __shared__ __align__(16) uint16_t Vs[2][4096];
  const int tid = threadIdx.x;
  const int wave = tid >> 6;
  const int lane = tid & 63;
  const int quad = lane >> 4;
  const int l16 = lane & 15;
  const int bx = blockIdx.x;
  // bx = g*8 + xcd ; g = it + 32*hhi + 64*ib ; h = hhi*8 + xcd
  const int xcd = bx & 7;
  const int g = bx >> 3;
  const int it = g & 31;            // 32 i-tiles of 64 rows
  const int h = ((g >> 5) & 1) * 8 + xcd;
  const int ib = g >> 6;
  const int i0 = it * 64 + wave * 16;
  const size_t hb = (size_t)(ib * 16 + h) * 131072;

  // Q fragments (B-operand of S^T MFMA): lane l16 = q-row, k = quad*8+e
  short8 qf[2];
#pragma unroll
  for (int kc = 0; kc < 2; ++kc)
    qf[kc] = *(const short8*)(Qh + hb + (size_t)(i0 + l16) * 64 + kc * 32 + quad * 8);

  f32x4 o[4], o4;
  o4 = (f32x4){0.f, 0.f, 0.f, 0.f};
#pragma unroll
  for (int t = 0; t < 4; ++t) o[t] = (f32x4){0.f, 0.f, 0.f, 0.f};

  const short8 ones8 = {(short)0x3F80, (short)0x3F80, (short)0x3F80, (short)0x3F80,
                        (short)0x3F80, (short)0x3F80, (short)0x3F80, (short)0x3F80};

  // staging: this wave stages elems [wave*1024, wave*1024+1024) of each tile
  const uint16_t* gK = Kh + hb + wave * 1024 + lane * 8;
  const uint16_t* gV = Vh + hb + wave * 1024 + lane * 8;
  const int so = wave * 1024;

  // prologue: stage tile 0 into buf 0
  load_lds16(gK, &Ks[0][so]);
  load_lds16(gK + 512, &Ks[0][so + 512]);
  load_lds16(gV, &Vs[0][so]);
  load_lds16(gV + 512, &Vs[0][so + 512]);
  __syncthreads();

#pragma unroll 2
  for (int t = 0; t < 32; ++t) {
    const int cur = t & 1;
    // stage tile t+1 into the other buffer (hidden under this tile's compute)
    if (t < 31) {
      const size_t goff = (size_t)(t + 1) * 4096;
      load_lds16(gK + goff, &Ks[cur ^ 1][so]);
      load_lds16(gK + goff + 512, &Ks[cur ^ 1][so + 512]);
      load_lds16(gV + goff, &Vs[cur ^ 1][so]);
      load_lds16(gV + goff + 512, &Vs[cur ^ 1][so + 512]);
    }

    // K frags from LDS (same frag order as the global layout)
    short8 kf[8];
#pragma unroll
    for (int i = 0; i < 8; ++i) kf[i] = *(const short8*)&Ks[cur][i * 512 + lane * 8];

    // S^T = K . Q^T : lane holds q-row l16, j = st*16 + quad*4 + r
    f32x4 s[4];
#pragma unroll
    for (int st = 0; st < 4; ++st) {
      f32x4 sc = (f32x4){0.f, 0.f, 0.f, 0.f};
      sc = MFMA32(kf[st * 2 + 0], qf[0], sc);
      sc = MFMA32(kf[st * 2 + 1], qf[1], sc);
      s[st] = sc;
    }

    // V frags (sigma-permuted B-frags; i = st2*4 + dt)
    short8 v8[8];
#pragma unroll
    for (int i = 0; i < 8; ++i) v8[i] = *(const short8*)&Vs[cur][i * 512 + lane * 8];

    // P = exp2(s), packed straight into sigma-ordered x32 A-frags:
    // p8[st2][e] with e = h*4 + r <-> j = st2*32 + h*16 + quad*4 + r
    short8 p8[2];
#pragma unroll
    for (int st2 = 0; st2 < 2; ++st2) {
      short8 p;
#pragma unroll
      for (int hh = 0; hh < 2; ++hh)
#pragma unroll
        for (int r = 0; r < 4; ++r)
          p[hh * 4 + r] =
              (short)f32_to_bf16_fast(__builtin_amdgcn_exp2f(s[st2 * 2 + hh][r]));
      p8[st2] = p;
    }

    // O += P V via MFMA32 (8 PV + 2 row-sum per tile)
#pragma unroll
    for (int st2 = 0; st2 < 2; ++st2) {
      o4 = MFMA32(p8[st2], ones8, o4);
#pragma unroll
      for (int dt = 0; dt < 4; ++dt)
        o[dt] = MFMA32(p8[st2], v8[st2 * 4 + dt], o[dt]);
    }

    __syncthreads();
  }

  // epilogue: O /= l, store bf16 [B*2048][1024]
#pragma unroll
  for (int r = 0; r < 4; ++r) {
    const float inv = 1.0f / o4[r];
    const int row = i0 + quad * 4 + r;
    const size_t obase = (size_t)(ib * 2048 + row) * 1024 + h * 64;
#pragma unroll
    for (int tt = 0; tt < 4; ++tt)
      out[obase + tt * 16 + l16] = f32_to_bf16(o[tt][r] * inv);
  }
}

// ---------------- launch ----------------
extern "C" void kernel_launch(void* const* d_in, const int* in_sizes, int n_in,
                              void* d_out, int out_size, void* d_ws, size_t ws_size,
                              hipStream_t stream) {
  const float* x = (const float*)d_in[0];     // [2,2048,1024]
  const float* Wqkv = (const float*)d_in[1];  // [3072,1024]
  const float* Wout = (const float*)d_in[2];  // [1024,1024]
  const float* bout = (const float*)d_in[3];  // [1024]

  uint16_t* xb = (uint16_t*)d_ws;                       // 4096*1024
  uint16_t* wqkvb = xb + (size_t)4096 * 1024;           // 3072*1024
  uint16_t* woutb = wqkvb + (size_t)3072 * 1024;        // 1024*1024
  uint16_t* qh = woutb + (size_t)1024 * 1024;           // 32 heads * 131072
  uint16_t* kh = qh + (size_t)32 * 131072;
  uint16_t* vh = kh + (size_t)32 * 131072;
  uint16_t* attnb = vh + (size_t)32 * 131072;           // 4096*1024

  cvt3_kernel<<<8192, 256, 0, stream>>>(x, Wqkv, Wout, xb, wqkvb, woutb);

  gemm_qkv_kernel<<<dim3(4096 / 128, 3072 / 128), 256, 0, stream>>>(
      xb, wqkvb, qh, kh, vh);

  attn_kernel<<<1024, 256, 0, stream>>>(qh, kh, vh, attnb);

  gemm_out_kernel<<<dim3(4096 / 128, 1024 / 64), 256, 0, stream>>>(
      attnb, woutb, (float*)d_out, bout);
}